// Round 4
// baseline (60.864 us; speedup 1.0000x reference)
//
#include <hip/hip_runtime.h>

#define DW 512
#define DH 512
#define RROWS 8
#define BORDER (-2.0f)

typedef float v4f __attribute__((ext_vector_type(4)));

__device__ __forceinline__ float max3(float a, float b, float c) {
    return fmaxf(fmaxf(a, b), c);
}

// One wave (64 lanes x 8 cols) covers a full 512-wide row.
// Left/right neighbors come from adjacent lanes via shfl - zero edge loads.
__global__ __launch_bounds__(256) void dilate3x3_kernel(
    const float* __restrict__ in, float* __restrict__ out) {
    const int lane = threadIdx.x;                  // 0..63
    const int wid  = threadIdx.y;                  // 0..3
    const int x0   = lane << 3;                    // 8 columns per lane
    const int y0   = (blockIdx.y * 4 + wid) * RROWS;
    const int img  = blockIdx.z;

    const float* __restrict__ p = in  + (size_t)img * DH * DW;
    float*       __restrict__ q = out + (size_t)img * DH * DW;

    float h[3][8];                                 // rolling horizontal-max rows

    auto loadrow = [&](int y, float hv[8]) {
        if (y < 0 || y >= DH) {
            #pragma unroll
            for (int i = 0; i < 8; ++i) hv[i] = BORDER;
            return;
        }
        const float* row = p + (size_t)y * DW + x0;
        v4f a = *reinterpret_cast<const v4f*>(row);
        v4f b = *reinterpret_cast<const v4f*>(row + 4);
        // neighbor words from adjacent lanes (full wave active)
        float left  = __shfl(b.w, (lane + 63) & 63);
        float right = __shfl(a.x, (lane + 1) & 63);
        if (lane == 0)  left  = BORDER;
        if (lane == 63) right = BORDER;
        hv[0] = max3(left, a.x, a.y);
        hv[1] = max3(a.x, a.y, a.z);
        hv[2] = max3(a.y, a.z, a.w);
        hv[3] = max3(a.z, a.w, b.x);
        hv[4] = max3(a.w, b.x, b.y);
        hv[5] = max3(b.x, b.y, b.z);
        hv[6] = max3(b.y, b.z, b.w);
        hv[7] = max3(b.z, b.w, right);
    };

    loadrow(y0 - 1, h[0]);
    loadrow(y0,     h[1]);

    #pragma unroll
    for (int r = 0; r < RROWS; ++r) {
        loadrow(y0 + r + 1, h[(r + 2) % 3]);
        v4f o0, o1;
        o0.x = max3(h[0][0], h[1][0], h[2][0]);
        o0.y = max3(h[0][1], h[1][1], h[2][1]);
        o0.z = max3(h[0][2], h[1][2], h[2][2]);
        o0.w = max3(h[0][3], h[1][3], h[2][3]);
        o1.x = max3(h[0][4], h[1][4], h[2][4]);
        o1.y = max3(h[0][5], h[1][5], h[2][5]);
        o1.z = max3(h[0][6], h[1][6], h[2][6]);
        o1.w = max3(h[0][7], h[1][7], h[2][7]);
        float* dst = q + (size_t)(y0 + r) * DW + x0;
        __builtin_nontemporal_store(o0, reinterpret_cast<v4f*>(dst));
        __builtin_nontemporal_store(o1, reinterpret_cast<v4f*>(dst + 4));
    }
}

extern "C" void kernel_launch(void* const* d_in, const int* in_sizes, int n_in,
                              void* d_out, int out_size, void* d_ws, size_t ws_size,
                              hipStream_t stream) {
    const float* img = (const float*)d_in[0];
    float* out = (float*)d_out;

    const int n_imgs = in_sizes[0] / (DH * DW);    // 16*8 = 128

    dim3 block(64, 4, 1);                          // 4 waves; each wave owns full rows
    dim3 grid(1, DH / (RROWS * 4), n_imgs);        // (1, 16, 128)
    dilate3x3_kernel<<<grid, block, 0, stream>>>(img, out);
}

// Round 5
// 49.131 us; speedup vs baseline: 1.2388x; 1.2388x over previous
//
#include <hip/hip_runtime.h>

#define DW 512
#define DH 512
#define RROWS 8
#define BORDER (-2.0f)

typedef float v4f __attribute__((ext_vector_type(4)));

__device__ __forceinline__ float max3f(float a, float b, float c) {
    return fmaxf(fmaxf(a, b), c);
}

// Separable dilation, vertical-first: each lane owns 4 contiguous columns
// (perfect 16B/lane coalescing, 128 tx = full 512-wide row). Vertical max
// needs no neighbors (1 dwordx4 per row); horizontal max runs on the
// vertical-max registers via intra-wave shfl. Only the half-row boundary
// column (255/256) needs a 1-lane masked scalar load per row.
__global__ __launch_bounds__(256) void dilate3x3_kernel(
    const float* __restrict__ in, float* __restrict__ out) {
    const int tx   = threadIdx.x;              // 0..127
    const int lane = tx & 63;
    const int x0   = tx << 2;
    const int rowgrp = blockIdx.y * blockDim.y + threadIdx.y;
    const int y0   = rowgrp * RROWS;
    const int img  = blockIdx.z;

    const float* __restrict__ p = in  + (size_t)img * DH * DW;
    float*       __restrict__ q = out + (size_t)img * DH * DW;

    // which lanes need the cross-wave boundary word, and which column
    const bool needL = (lane == 0  && x0 == 256);       // right-half wave: col 255
    const bool needR = (lane == 63 && x0 + 4 == 256);   // left-half wave: col 256
    const bool needE = needL || needR;
    const int  ex    = needL ? 255 : 256;

    v4f  raw[3];
    float e[3];

    auto loadrow = [&](int idx, int y) {
        if (y < 0 || y >= DH) {
            raw[idx] = (v4f)BORDER;
            e[idx]   = BORDER;
            return;
        }
        const float* row = p + (size_t)y * DW;
        raw[idx] = *reinterpret_cast<const v4f*>(row + x0);
        if (needE) e[idx] = row[ex];               // 1 active lane per wave
    };

    loadrow(0, y0 - 1);
    loadrow(1, y0);

    #pragma unroll
    for (int r = 0; r < RROWS; ++r) {
        loadrow((r + 2) % 3, y0 + r + 1);
        // vertical max (order-independent across the rolling buffer)
        v4f vm;
        vm.x = max3f(raw[0].x, raw[1].x, raw[2].x);
        vm.y = max3f(raw[0].y, raw[1].y, raw[2].y);
        vm.z = max3f(raw[0].z, raw[1].z, raw[2].z);
        vm.w = max3f(raw[0].w, raw[1].w, raw[2].w);
        float em = max3f(e[0], e[1], e[2]);        // boundary-column vmax (valid on needE lanes)
        // horizontal neighbors of the vertical max via intra-wave shuffles
        float ln = __shfl(vm.w, (lane + 63) & 63);
        float rn = __shfl(vm.x, (lane + 1) & 63);
        float left  = (lane == 0)  ? ((x0 == 0)       ? BORDER : em) : ln;
        float right = (lane == 63) ? ((x0 + 4 == DW)  ? BORDER : em) : rn;
        v4f o;
        o.x = max3f(left, vm.x, vm.y);
        o.y = max3f(vm.x, vm.y, vm.z);
        o.z = max3f(vm.y, vm.z, vm.w);
        o.w = max3f(vm.z, vm.w, right);
        __builtin_nontemporal_store(o,
            reinterpret_cast<v4f*>(q + (size_t)(y0 + r) * DW + x0));
    }
}

extern "C" void kernel_launch(void* const* d_in, const int* in_sizes, int n_in,
                              void* d_out, int out_size, void* d_ws, size_t ws_size,
                              hipStream_t stream) {
    const float* img = (const float*)d_in[0];
    float* out = (float*)d_out;

    const int n_imgs = in_sizes[0] / (DH * DW);    // 16*8 = 128

    dim3 block(128, 2, 1);                         // 256 threads, 4 waves
    dim3 grid(1, DH / (RROWS * 2), n_imgs);        // (1, 32, 128)
    dilate3x3_kernel<<<grid, block, 0, stream>>>(img, out);
}

// Round 6
// 46.416 us; speedup vs baseline: 1.3113x; 1.0585x over previous
//
#include <hip/hip_runtime.h>

#define DW 512
#define DH 512
#define RROWS 8
#define BORDER (-2.0f)

typedef float v4f __attribute__((ext_vector_type(4)));

__device__ __forceinline__ float max3f(float a, float b, float c) {
    return fmaxf(fmaxf(a, b), c);
}

// Separable dilation, vertical-first, ALL 10 row-loads issued upfront for
// maximum memory-level parallelism. Each lane owns 4 contiguous columns
// (16B/lane, 128 tx = full 512-wide row). Horizontal max via intra-wave
// shfl on the vertical-max registers; half-row boundary column (255/256)
// via a 1-lane exec-masked scalar load per row.
__global__ __launch_bounds__(256) void dilate3x3_kernel(
    const float* __restrict__ in, float* __restrict__ out) {
    const int tx   = threadIdx.x;              // 0..127
    const int lane = tx & 63;
    const int x0   = tx << 2;
    const int rowgrp = blockIdx.y * blockDim.y + threadIdx.y;
    const int y0   = rowgrp * RROWS;
    const int img  = blockIdx.z;

    const float* __restrict__ p = in  + (size_t)img * DH * DW;
    float*       __restrict__ q = out + (size_t)img * DH * DW;

    const bool needL = (lane == 0  && x0 == 256);       // right-half wave: col 255
    const bool needR = (lane == 63 && x0 + 4 == 256);   // left-half wave: col 256
    const bool needE = needL || needR;
    const int  ex    = needL ? 255 : 256;

    v4f   raw[RROWS + 2];
    float e[RROWS + 2];

    // Issue all 10 row loads back-to-back (static indices, fully unrolled).
    #pragma unroll
    for (int i = 0; i < RROWS + 2; ++i) {
        const int y = y0 - 1 + i;
        if (y < 0 || y >= DH) {
            raw[i] = (v4f)BORDER;
            e[i]   = BORDER;
        } else {
            const float* row = p + (size_t)y * DW;
            raw[i] = *reinterpret_cast<const v4f*>(row + x0);
            e[i]   = needE ? row[ex] : BORDER;   // exec-masked: 1 lane/wave
        }
    }

    #pragma unroll
    for (int r = 0; r < RROWS; ++r) {
        v4f vm;
        vm.x = max3f(raw[r].x, raw[r + 1].x, raw[r + 2].x);
        vm.y = max3f(raw[r].y, raw[r + 1].y, raw[r + 2].y);
        vm.z = max3f(raw[r].z, raw[r + 1].z, raw[r + 2].z);
        vm.w = max3f(raw[r].w, raw[r + 1].w, raw[r + 2].w);
        float em = max3f(e[r], e[r + 1], e[r + 2]);
        float ln = __shfl(vm.w, (lane + 63) & 63);
        float rn = __shfl(vm.x, (lane + 1) & 63);
        float left  = (lane == 0)  ? ((x0 == 0)      ? BORDER : em) : ln;
        float right = (lane == 63) ? ((x0 + 4 == DW) ? BORDER : em) : rn;
        v4f o;
        o.x = max3f(left, vm.x, vm.y);
        o.y = max3f(vm.x, vm.y, vm.z);
        o.z = max3f(vm.y, vm.z, vm.w);
        o.w = max3f(vm.z, vm.w, right);
        __builtin_nontemporal_store(o,
            reinterpret_cast<v4f*>(q + (size_t)(y0 + r) * DW + x0));
    }
}

extern "C" void kernel_launch(void* const* d_in, const int* in_sizes, int n_in,
                              void* d_out, int out_size, void* d_ws, size_t ws_size,
                              hipStream_t stream) {
    const float* img = (const float*)d_in[0];
    float* out = (float*)d_out;

    const int n_imgs = in_sizes[0] / (DH * DW);    // 16*8 = 128

    dim3 block(128, 2, 1);                         // 256 threads, 4 waves
    dim3 grid(1, DH / (RROWS * 2), n_imgs);        // (1, 32, 128)
    dilate3x3_kernel<<<grid, block, 0, stream>>>(img, out);
}

// Round 7
// 46.047 us; speedup vs baseline: 1.3218x; 1.0080x over previous
//
#include <hip/hip_runtime.h>

#define DW 512
#define DH 512
#define RROWS 16
#define BORDER (-2.0f)

typedef float v4f __attribute__((ext_vector_type(4)));

__device__ __forceinline__ float max3f(float a, float b, float c) {
    return fmaxf(fmaxf(a, b), c);
}

// Separable dilation, vertical-first, ALL 18 row-loads issued upfront for
// maximum memory-level parallelism (18 KB in flight per wave). Each lane
// owns 4 contiguous columns (16B/lane, 128 tx = full 512-wide row).
// Horizontal max via intra-wave shfl on the vertical-max registers;
// half-row boundary column (255/256) via a 1-lane masked scalar load.
__global__ __launch_bounds__(256) void dilate3x3_kernel(
    const float* __restrict__ in, float* __restrict__ out) {
    const int tx   = threadIdx.x;              // 0..127
    const int lane = tx & 63;
    const int x0   = tx << 2;
    const int rowgrp = blockIdx.y * blockDim.y + threadIdx.y;
    const int y0   = rowgrp * RROWS;
    const int img  = blockIdx.z;

    const float* __restrict__ p = in  + (size_t)img * DH * DW;
    float*       __restrict__ q = out + (size_t)img * DH * DW;

    const bool needL = (lane == 0  && x0 == 256);       // right-half wave: col 255
    const bool needR = (lane == 63 && x0 + 4 == 256);   // left-half wave: col 256
    const bool needE = needL || needR;
    const int  ex    = needL ? 255 : 256;

    v4f   raw[RROWS + 2];
    float e[RROWS + 2];

    // Issue all row loads back-to-back (static indices, fully unrolled).
    #pragma unroll
    for (int i = 0; i < RROWS + 2; ++i) {
        const int y = y0 - 1 + i;
        if (y < 0 || y >= DH) {
            raw[i] = (v4f)BORDER;
            e[i]   = BORDER;
        } else {
            const float* row = p + (size_t)y * DW;
            raw[i] = *reinterpret_cast<const v4f*>(row + x0);
            e[i]   = needE ? row[ex] : BORDER;   // exec-masked: 1 lane/wave
        }
    }

    #pragma unroll
    for (int r = 0; r < RROWS; ++r) {
        v4f vm;
        vm.x = max3f(raw[r].x, raw[r + 1].x, raw[r + 2].x);
        vm.y = max3f(raw[r].y, raw[r + 1].y, raw[r + 2].y);
        vm.z = max3f(raw[r].z, raw[r + 1].z, raw[r + 2].z);
        vm.w = max3f(raw[r].w, raw[r + 1].w, raw[r + 2].w);
        float em = max3f(e[r], e[r + 1], e[r + 2]);
        float ln = __shfl(vm.w, (lane + 63) & 63);
        float rn = __shfl(vm.x, (lane + 1) & 63);
        float left  = (lane == 0)  ? ((x0 == 0)      ? BORDER : em) : ln;
        float right = (lane == 63) ? ((x0 + 4 == DW) ? BORDER : em) : rn;
        v4f o;
        o.x = max3f(left, vm.x, vm.y);
        o.y = max3f(vm.x, vm.y, vm.z);
        o.z = max3f(vm.y, vm.z, vm.w);
        o.w = max3f(vm.z, vm.w, right);
        __builtin_nontemporal_store(o,
            reinterpret_cast<v4f*>(q + (size_t)(y0 + r) * DW + x0));
    }
}

extern "C" void kernel_launch(void* const* d_in, const int* in_sizes, int n_in,
                              void* d_out, int out_size, void* d_ws, size_t ws_size,
                              hipStream_t stream) {
    const float* img = (const float*)d_in[0];
    float* out = (float*)d_out;

    const int n_imgs = in_sizes[0] / (DH * DW);    // 16*8 = 128

    dim3 block(128, 2, 1);                         // 256 threads, 4 waves
    dim3 grid(1, DH / (RROWS * 2), n_imgs);        // (1, 16, 128)
    dilate3x3_kernel<<<grid, block, 0, stream>>>(img, out);
}